// Round 3
// baseline (74427.100 us; speedup 1.0000x reference)
//
#include <hip/hip_runtime.h>
#include <math.h>

#define SEQ    8192
#define NSTEPS 2048
#define NTOT   (SEQ + NSTEPS)   // 10240 unified steps per layer (open-loop + AR)
#define IDIM   256
#define HDIM   1024

#define NWG    128      // 32 WGs per layer
#define TPB    256      // 4 waves per WG: all capture, all compute (no idle waves)
#define WPB    4
#define RD     32       // ring depth (power of 2) — deep credit, gate rarely binds
#define CREDIT (RD - 8) // slack 8 below RD covers publishes in flight + stale minp

typedef unsigned long long u64;

// ---- workspace layout (floats) ----
// WT: 8 slots [1024][1024] transposed weights: slot(2i)=A_i cols, slot(2i+1)=B_i cols
//     A_0 = W_fused = out_W^T @ Wx0 (AR phase); A_i = Wx_rest[i-1]; B_i = Wh matrices
// BF:  b_fused[1024]
// RING: 4 layers x RD slots x 1024 u64; u64 = (step_tag<<32)|f32bits
// PROG: NWG u32, per-WG progress (step whose inputs are fully captured)
#define WT_FLOATS   (8ull*HDIM*HDIM)
#define BF_FLOAT    WT_FLOATS
#define RING_FLOAT  (WT_FLOATS + HDIM)
#define RING_U64S   (4ull*RD*HDIM)          // 131072
#define PROG_FLOAT  (RING_FLOAT + 2ull*RING_U64S)

// ---------------- setup kernels ----------------

__global__ void k_fuse_w(const float* __restrict__ outW, const float* __restrict__ Wx0,
                         float* __restrict__ ws) {
    int l = blockIdx.x * 256 + threadIdx.x;   // grid (4, 1024)
    int j = blockIdx.y;
    float acc = 0.f;
    for (int k = 0; k < IDIM; ++k)
        acc += outW[(size_t)k * HDIM + l] * Wx0[(size_t)k * HDIM + j];
    ws[(size_t)j * HDIM + l] = acc;
}

__global__ void k_fuse_b(const float* __restrict__ b0, const float* __restrict__ outb,
                         const float* __restrict__ Wx0, float* __restrict__ ws) {
    int j = blockIdx.x * 256 + threadIdx.x;   // grid (4)
    float acc = b0[j];
    for (int k = 0; k < IDIM; ++k)
        acc += outb[k] * Wx0[(size_t)k * HDIM + j];
    ws[BF_FLOAT + j] = acc;
}

__global__ void k_pack(const float* __restrict__ Wh0, const float* __restrict__ Wxr,
                       const float* __restrict__ Whr, float* __restrict__ ws) {
    __shared__ float t[32][33];
    int z = blockIdx.z;
    const float* src; int slot;
    if (z == 0)      { src = Wh0;                                  slot = 1; }
    else if (z <= 3) { src = Wxr + (size_t)(z - 1) * HDIM * HDIM;  slot = 2 * z; }
    else             { src = Whr + (size_t)(z - 4) * HDIM * HDIM;  slot = 2 * (z - 4) + 3; }
    int j0 = blockIdx.x * 32, l0 = blockIdx.y * 32;
    t[threadIdx.y][threadIdx.x] = src[(size_t)(l0 + threadIdx.y) * HDIM + j0 + threadIdx.x];
    __syncthreads();
    float* dst = ws + (size_t)slot * HDIM * HDIM;
    dst[(size_t)(j0 + threadIdx.y) * HDIM + (l0 + threadIdx.x)] = t[threadIdx.x][threadIdx.y];
}

// zero ring tags + progress (every launch; ws is re-poisoned before each)
__global__ void k_init(float* __restrict__ ws) {
    int t = blockIdx.x * blockDim.x + threadIdx.x;   // grid(256) x 512 = 131072 == RING_U64S
    ((u64*)(ws + RING_FLOAT))[t] = 0ull;             // tag 0, value 0.0 == initial h state
    if (t < NWG) ((unsigned*)(ws + PROG_FLOAT))[t] = 0u;
}

// ---------------- scan kernel ----------------

__device__ __forceinline__ float wsum(float v) {
#pragma unroll
    for (int off = 32; off > 0; off >>= 1) v += __shfl_xor(v, off, 64);
    return v;
}

__device__ __forceinline__ int wmin(int v) {
#pragma unroll
    for (int off = 32; off > 0; off >>= 1) {
        int o = __shfl_xor(v, off, 64);
        v = o < v ? o : v;
    }
    return v;
}

__device__ __forceinline__ float ftanh(float x) {
    x = fminf(15.f, fmaxf(-15.f, x));
    float e = __builtin_amdgcn_exp2f(x * 2.8853900817779268f);   // e^{2x}
    return (e - 1.f) * __builtin_amdgcn_rcpf(e + 1.f);
}

// Masked capture of 8 tagged elements, software-pipelined 2-deep: two load
// batches in flight so the tag check cadence is ~half a round-trip instead of
// a full one. Shorter cadence = earlier detect AND tighter detect-time
// distribution across the 32 consumer WGs (shrinks the max-of-32 publish
// spread on the next hop). Payload rides with the tag in one u64, so a
// matching check already holds the value.
__device__ __forceinline__ void capture8(const u64* slot, unsigned want,
                                         float* dst, int lane, int kbase) {
    const u64* p = slot + lane + 64 * kbase;
    unsigned done = 0;
    u64 va[8];
#pragma unroll
    for (int k = 0; k < 8; ++k)
        va[k] = __hip_atomic_load(p + 64 * k, __ATOMIC_RELAXED, __HIP_MEMORY_SCOPE_AGENT);
    for (;;) {
        u64 vb[8];
#pragma unroll
        for (int k = 0; k < 8; ++k) {
            vb[k] = 0;
            if (!(done & (1u << k)))
                vb[k] = __hip_atomic_load(p + 64 * k, __ATOMIC_RELAXED, __HIP_MEMORY_SCOPE_AGENT);
        }
#pragma unroll
        for (int k = 0; k < 8; ++k) {
            if (!(done & (1u << k)) && ((unsigned)(va[k] >> 32) == want)) {
                dst[lane + 64 * (kbase + k)] = __uint_as_float((unsigned)va[k]);
                done |= 1u << k;
            }
        }
        if (__all(done == 0xFFu)) return;
#pragma unroll
        for (int k = 0; k < 8; ++k) {
            va[k] = 0;
            if (!(done & (1u << k)))
                va[k] = __hip_atomic_load(p + 64 * k, __ATOMIC_RELAXED, __HIP_MEMORY_SCOPE_AGENT);
        }
#pragma unroll
        for (int k = 0; k < 8; ++k) {
            if (!(done & (1u << k)) && ((unsigned)(vb[k] >> 32) == want)) {
                dst[lane + 64 * (kbase + k)] = __uint_as_float((unsigned)vb[k]);
                done |= 1u << k;
            }
        }
        if (__all(done == 0xFFu)) return;
    }
}

__global__ __launch_bounds__(TPB, 1) void k_scan(
    const float* __restrict__ xs, const float* __restrict__ Wx0,
    const float* __restrict__ b0, const float* __restrict__ brest,
    const float* __restrict__ outW, const float* __restrict__ outb,
    float* __restrict__ ws, float* __restrict__ out)
{
    const int lane  = threadIdx.x & 63;
    const int wv    = threadIdx.x >> 6;     // 0..3
    const int layer = blockIdx.x >> 5;      // 32 WGs per layer
    const int wgl   = blockIdx.x & 31;
    const int jw    = wgl * WPB + wv;       // wave index within layer, 0..127
    const int j0    = jw * 8;               // owns columns j0..j0+7

    __shared__ float ldsOwn[2][HDIM];       // own layer h^{n-1}, parity double-buffered
    __shared__ float ldsUp[2][HDIM];        // upstream input vector

    u64* ring = (u64*)(ws + RING_FLOAT);
    unsigned* prog = (unsigned*)(ws + PROG_FLOAT);
    const int cons = (layer + 1) & 3;       // downstream ring consumer layer

    // ---- one-time weight preload into VGPRs ----
    float A[8][16], B[8][16];
#pragma unroll
    for (int c = 0; c < 8; ++c)
#pragma unroll
        for (int k = 0; k < 16; ++k) {
            A[c][k] = ws[((size_t)(2 * layer) * HDIM + (j0 + c)) * HDIM + lane + 64 * k];
            B[c][k] = ws[((size_t)(2 * layer + 1) * HDIM + (j0 + c)) * HDIM + lane + 64 * k];
        }
    float wx0[8][4];
    if (layer == 0) {
#pragma unroll
        for (int c = 0; c < 8; ++c)
#pragma unroll
            for (int k = 0; k < 4; ++k)
                wx0[c][k] = Wx0[(size_t)(lane + 64 * k) * HDIM + (j0 + c)];
    }
    float ow0[16], ow1[16]; float ob0 = 0.f, ob1 = 0.f;
    if (layer == 3) {       // each layer-3 wave owns two output rows (2jw, 2jw+1)
#pragma unroll
        for (int k = 0; k < 16; ++k) {
            ow0[k] = outW[(size_t)(2 * jw)     * HDIM + lane + 64 * k];
            ow1[k] = outW[(size_t)(2 * jw + 1) * HDIM + lane + 64 * k];
        }
        ob0 = outb[2 * jw]; ob1 = outb[2 * jw + 1];
    }
    float bb[8], bfc[8];
#pragma unroll
    for (int c = 0; c < 8; ++c) {
        bb[c]  = (layer == 0) ? b0[j0 + c] : brest[(size_t)(layer - 1) * HDIM + j0 + c];
        bfc[c] = (layer == 0) ? ws[BF_FLOAT + j0 + c] : 0.f;
    }

    // xs software pipeline: xv holds row n-1 for step n (preload row 0 here)
    float xv[4] = {0.f, 0.f, 0.f, 0.f}, xp[4] = {0.f, 0.f, 0.f, 0.f};
    if (layer == 0) {
#pragma unroll
        for (int k = 0; k < 4; ++k) xv[k] = xs[lane + 64 * k];
    }

    int minp = 0;   // cached min consumer progress (credit-based flow control)

    for (int n = 1; n <= NTOT; ++n) {
        const int par = n & 1;
        const bool xphase = (layer == 0) && (n <= SEQ);

        // backpressure (rare with deep ring): writing slot n kills tag n-RD;
        // downstream consumer must be past n-CREDIT. Own-layer skew is
        // self-limited (peers are >= step n-1 when we reach step n).
        if (minp < n - CREDIT) {
            for (;;) {
                unsigned pv = __hip_atomic_load(&prog[cons * 32 + (lane & 31)],
                                                __ATOMIC_RELAXED, __HIP_MEMORY_SCOPE_AGENT);
                minp = wmin((int)pv);
                if (minp >= n - CREDIT) break;
                __builtin_amdgcn_s_sleep(2);
            }
        }

        // parallel captures: waves 0-1 own-state halves, waves 2-3 upstream halves
        if (wv < 2) {
            capture8(ring + ((size_t)layer * RD + ((n - 1) & (RD - 1))) * HDIM,
                     (unsigned)(n - 1), ldsOwn[par], lane, wv * 8);
        } else if (!xphase) {
            const int ul = (layer == 0) ? 3 : layer - 1;
            const unsigned want = (layer == 0) ? (unsigned)(n - 1) : (unsigned)n;
            capture8(ring + ((size_t)ul * RD + (want & (RD - 1))) * HDIM,
                     want, ldsUp[par], lane, (wv - 2) * 8);
        }
        __syncthreads();
        if (threadIdx.x == 0)
            __hip_atomic_store(&prog[blockIdx.x], (unsigned)n, __ATOMIC_RELAXED, __HIP_MEMORY_SCOPE_AGENT);

        // issue next-step xs loads AFTER the barrier: the per-step vmcnt(0)
        // drain sits before s_barrier, so these get a full cell of slack
        if (xphase && n < SEQ) {
            const float* xr = xs + (size_t)n * IDIM;    // row n, consumed at step n+1
#pragma unroll
            for (int k = 0; k < 4; ++k) xp[k] = xr[lane + 64 * k];
        }

        // compute this wave's 8 columns
        float acc[8];
#pragma unroll
        for (int c = 0; c < 8; ++c) acc[c] = 0.f;
        if (xphase) {
#pragma unroll
            for (int k = 0; k < 4; ++k) {
                float x = xv[k];
#pragma unroll
                for (int c = 0; c < 8; ++c) acc[c] += x * wx0[c][k];
            }
        } else {
#pragma unroll
            for (int k = 0; k < 16; ++k) {
                float x = ldsUp[par][lane + 64 * k];
#pragma unroll
                for (int c = 0; c < 8; ++c) acc[c] += x * A[c][k];
            }
        }
#pragma unroll
        for (int k = 0; k < 16; ++k) {
            float y = ldsOwn[par][lane + 64 * k];
#pragma unroll
            for (int c = 0; c < 8; ++c) acc[c] += y * B[c][k];
        }
#pragma unroll
        for (int c = 0; c < 8; ++c) acc[c] = wsum(acc[c]);
        const bool fph = (layer == 0) && (n > SEQ);
        float r[8];
#pragma unroll
        for (int c = 0; c < 8; ++c) r[c] = ftanh(acc[c] + (fph ? bfc[c] : bb[c]));

        // publish tagged results (lanes 0..7 store one column each; select via
        // unrolled cndmask chain — no runtime-indexed array -> no scratch)
        {
            float rv = r[0];
#pragma unroll
            for (int c = 1; c < 8; ++c) rv = (lane == c) ? r[c] : rv;
            u64* dst = ring + ((size_t)layer * RD + (n & (RD - 1))) * HDIM + j0;
            if (lane < 8)
                __hip_atomic_store(dst + lane,
                                   ((u64)(unsigned)n << 32) | (u64)__float_as_uint(rv),
                                   __ATOMIC_RELAXED, __HIP_MEMORY_SCOPE_AGENT);
        }

        // out row n-2 = ow . h3^{n-1}: operand already in ldsOwn — free handoff
        if (layer == 3 && n >= 2) {
            float o0 = 0.f, o1 = 0.f;
#pragma unroll
            for (int k = 0; k < 16; ++k) {
                float y = ldsOwn[par][lane + 64 * k];
                o0 += y * ow0[k]; o1 += y * ow1[k];
            }
            o0 = wsum(o0); o1 = wsum(o1);
            if (lane == 0) {
                out[(size_t)(n - 2) * IDIM + 2 * jw]     = o0 + ob0;
                out[(size_t)(n - 2) * IDIM + 2 * jw + 1] = o1 + ob1;
            }
        }

        // rotate xs pipeline (register copy; xp completed by compute-length slack)
        if (xphase && n < SEQ) {
#pragma unroll
            for (int k = 0; k < 4; ++k) xv[k] = xp[k];
        }
    }

    // epilogue: final output row from h3^{NTOT}
    if (layer == 3) {
        if (wv < 2)
            capture8(ring + ((size_t)3 * RD + (NTOT & (RD - 1))) * HDIM,
                     (unsigned)NTOT, ldsOwn[0], lane, wv * 8);
        __syncthreads();
        float o0 = 0.f, o1 = 0.f;
#pragma unroll
        for (int k = 0; k < 16; ++k) {
            float y = ldsOwn[0][lane + 64 * k];
            o0 += y * ow0[k]; o1 += y * ow1[k];
        }
        o0 = wsum(o0); o1 = wsum(o1);
        if (lane == 0) {
            out[(size_t)(NTOT - 1) * IDIM + 2 * jw]     = o0 + ob0;
            out[(size_t)(NTOT - 1) * IDIM + 2 * jw + 1] = o1 + ob1;
        }
    }
}

// ---------------- launcher ----------------

extern "C" void kernel_launch(void* const* d_in, const int* in_sizes, int n_in,
                              void* d_out, int out_size, void* d_ws, size_t ws_size,
                              hipStream_t stream) {
    (void)in_sizes; (void)n_in; (void)out_size; (void)ws_size;
    const float* xs   = (const float*)d_in[0];
    const float* Wx0  = (const float*)d_in[1];
    const float* Wh0  = (const float*)d_in[2];
    const float* b0   = (const float*)d_in[3];
    const float* Wxr  = (const float*)d_in[4];
    const float* Whr  = (const float*)d_in[5];
    const float* brst = (const float*)d_in[6];
    const float* outW = (const float*)d_in[7];
    const float* outb = (const float*)d_in[8];
    float* ws  = (float*)d_ws;
    float* out = (float*)d_out;

    k_fuse_w<<<dim3(4, HDIM), dim3(256), 0, stream>>>(outW, Wx0, ws);
    k_fuse_b<<<dim3(4), dim3(256), 0, stream>>>(b0, outb, Wx0, ws);
    k_pack<<<dim3(32, 32, 7), dim3(32, 32), 0, stream>>>(Wh0, Wxr, Whr, ws);
    k_init<<<dim3(256), dim3(512), 0, stream>>>(ws);

    void* args[] = { (void*)&xs, (void*)&Wx0, (void*)&b0, (void*)&brst,
                     (void*)&outW, (void*)&outb, (void*)&ws, (void*)&out };
    hipError_t e = hipLaunchCooperativeKernel((void*)k_scan, dim3(NWG), dim3(TPB),
                                              args, 0, stream);
    if (e != hipSuccess) {
        // fallback: plain launch (128 WGs, <=1 per CU, trivially co-resident)
        k_scan<<<dim3(NWG), dim3(TPB), 0, stream>>>(xs, Wx0, b0, brst, outW, outb, ws, out);
    }
}

// Round 4
// 44587.860 us; speedup vs baseline: 1.6692x; 1.6692x over previous
//
#include <hip/hip_runtime.h>
#include <math.h>

#define SEQ    8192
#define NSTEPS 2048
#define NTOT   (SEQ + NSTEPS)   // 10240 unified steps per layer (open-loop + AR)
#define IDIM   256
#define HDIM   1024

#define NWG    128      // 32 WGs per layer
#define TPB    512      // 8 waves per WG
#define WPB    8
#define RD     8        // ring depth (power of 2)

typedef unsigned long long u64;

// ---- workspace layout (floats) ----
// WT: 8 slots [1024][1024] transposed weights: slot(2i)=A_i cols, slot(2i+1)=B_i cols
//     A_0 = W_fused = out_W^T @ Wx0 (AR phase); A_i = Wx_rest[i-1]; B_i = Wh matrices
// BF:  b_fused[1024]
// RING: 4 layers x RD slots x 1024 u64; u64 = (step_tag<<32)|f32bits
// PROG: NWG u32, per-WG progress (step whose inputs are fully captured)
#define WT_FLOATS   (8ull*HDIM*HDIM)
#define BF_FLOAT    WT_FLOATS
#define RING_FLOAT  (WT_FLOATS + HDIM)
#define RING_U64S   (4ull*RD*HDIM)          // 32768
#define PROG_FLOAT  (RING_FLOAT + 2ull*RING_U64S)

// ---------------- setup kernels ----------------

__global__ void k_fuse_w(const float* __restrict__ outW, const float* __restrict__ Wx0,
                         float* __restrict__ ws) {
    int l = blockIdx.x * 256 + threadIdx.x;   // grid (4, 1024)
    int j = blockIdx.y;
    float acc = 0.f;
    for (int k = 0; k < IDIM; ++k)
        acc += outW[(size_t)k * HDIM + l] * Wx0[(size_t)k * HDIM + j];
    ws[(size_t)j * HDIM + l] = acc;
}

__global__ void k_fuse_b(const float* __restrict__ b0, const float* __restrict__ outb,
                         const float* __restrict__ Wx0, float* __restrict__ ws) {
    int j = blockIdx.x * 256 + threadIdx.x;   // grid (4)
    float acc = b0[j];
    for (int k = 0; k < IDIM; ++k)
        acc += outb[k] * Wx0[(size_t)k * HDIM + j];
    ws[BF_FLOAT + j] = acc;
}

__global__ void k_pack(const float* __restrict__ Wh0, const float* __restrict__ Wxr,
                       const float* __restrict__ Whr, float* __restrict__ ws) {
    __shared__ float t[32][33];
    int z = blockIdx.z;
    const float* src; int slot;
    if (z == 0)      { src = Wh0;                                  slot = 1; }
    else if (z <= 3) { src = Wxr + (size_t)(z - 1) * HDIM * HDIM;  slot = 2 * z; }
    else             { src = Whr + (size_t)(z - 4) * HDIM * HDIM;  slot = 2 * (z - 4) + 3; }
    int j0 = blockIdx.x * 32, l0 = blockIdx.y * 32;
    t[threadIdx.y][threadIdx.x] = src[(size_t)(l0 + threadIdx.y) * HDIM + j0 + threadIdx.x];
    __syncthreads();
    float* dst = ws + (size_t)slot * HDIM * HDIM;
    dst[(size_t)(j0 + threadIdx.y) * HDIM + (l0 + threadIdx.x)] = t[threadIdx.x][threadIdx.y];
}

// zero ring tags + progress (every launch; ws is re-poisoned before each)
__global__ void k_init(float* __restrict__ ws) {
    int t = blockIdx.x * blockDim.x + threadIdx.x;   // grid(64) x 512 = 32768 == RING_U64S
    ((u64*)(ws + RING_FLOAT))[t] = 0ull;             // tag 0, value 0.0 == initial h state
    if (t < NWG) ((unsigned*)(ws + PROG_FLOAT))[t] = 0u;
}

// ---------------- scan kernel ----------------

__device__ __forceinline__ float wsum(float v) {
#pragma unroll
    for (int off = 32; off > 0; off >>= 1) v += __shfl_xor(v, off, 64);
    return v;
}

__device__ __forceinline__ int wmin(int v) {
#pragma unroll
    for (int off = 32; off > 0; off >>= 1) {
        int o = __shfl_xor(v, off, 64);
        v = o < v ? o : v;
    }
    return v;
}

__device__ __forceinline__ float ftanh(float x) {
    x = fminf(15.f, fmaxf(-15.f, x));
    float e = __builtin_amdgcn_exp2f(x * 2.8853900817779268f);   // e^{2x}
    return (e - 1.f) * __builtin_amdgcn_rcpf(e + 1.f);
}

// Cheap pre-gate for a capture: wait until every producer WG of layer `pl`
// has reached step `want` in its own capture phase (prog is stored ~compute
// time BEFORE the matching publish). Polls 32 dwords (2 cache lines) per
// cadence instead of 4 KB of tagged data per wave — ~50x less LLC poll
// traffic while an operand is not yet due. Purely an optimization: capture8
// still tag-verifies every element, so gate timing cannot affect correctness.
__device__ __forceinline__ void progGate(const unsigned* prog, int pl, int want, int lane) {
    if (want <= 0) return;
    for (;;) {
        unsigned pv = __hip_atomic_load(&prog[pl * 32 + (lane & 31)],
                                        __ATOMIC_RELAXED, __HIP_MEMORY_SCOPE_AGENT);
        if (wmin((int)pv) >= want) return;
        __builtin_amdgcn_s_sleep(1);
    }
}

// Masked incremental capture of 8 tagged elements (k = kbase..kbase+7) per lane.
// Only not-yet-tagged elements are reloaded (predicated, concurrent issue).
// Detecting iteration already holds the payload (tag+value atomic in one u64).
__device__ __forceinline__ void capture8(const u64* slot, unsigned want,
                                         float* dst, int lane, int kbase) {
    unsigned done = 0;
    for (;;) {
        u64 v[8];
#pragma unroll
        for (int k = 0; k < 8; ++k) {
            v[k] = 0;
            if (!(done & (1u << k)))
                v[k] = __hip_atomic_load(slot + lane + 64 * (kbase + k),
                                         __ATOMIC_RELAXED, __HIP_MEMORY_SCOPE_AGENT);
        }
#pragma unroll
        for (int k = 0; k < 8; ++k) {
            if (!(done & (1u << k)) && ((unsigned)(v[k] >> 32) == want)) {
                dst[lane + 64 * (kbase + k)] = __uint_as_float((unsigned)v[k]);
                done |= 1u << k;
            }
        }
        if (__all(done == 0xFFu)) return;
    }
}

__global__ __launch_bounds__(TPB, 1) void k_scan(
    const float* __restrict__ xs, const float* __restrict__ Wx0,
    const float* __restrict__ b0, const float* __restrict__ brest,
    const float* __restrict__ outW, const float* __restrict__ outb,
    float* __restrict__ ws, float* __restrict__ out)
{
    const int lane  = threadIdx.x & 63;
    const int wv    = threadIdx.x >> 6;
    const int layer = blockIdx.x >> 5;      // 32 WGs per layer
    const int wgl   = blockIdx.x & 31;
    const int jw    = wgl * WPB + wv;       // wave index within layer, 0..255
    const int j0    = jw * 4;               // owns columns j0..j0+3

    __shared__ float ldsOwn[2][HDIM];       // own layer h^{n-1}, parity double-buffered
    __shared__ float ldsUp[2][HDIM];        // upstream input vector

    u64* ring = (u64*)(ws + RING_FLOAT);
    unsigned* prog = (unsigned*)(ws + PROG_FLOAT);
    const int cons = (layer + 1) & 3;       // downstream ring consumer layer

    // ---- one-time weight preload into VGPRs ----
    float A[4][16], B[4][16];
#pragma unroll
    for (int c = 0; c < 4; ++c)
#pragma unroll
        for (int k = 0; k < 16; ++k) {
            A[c][k] = ws[((size_t)(2 * layer) * HDIM + (j0 + c)) * HDIM + lane + 64 * k];
            B[c][k] = ws[((size_t)(2 * layer + 1) * HDIM + (j0 + c)) * HDIM + lane + 64 * k];
        }
    float wx0[4][4];
    if (layer == 0) {
#pragma unroll
        for (int c = 0; c < 4; ++c)
#pragma unroll
            for (int k = 0; k < 4; ++k)
                wx0[c][k] = Wx0[(size_t)(lane + 64 * k) * HDIM + (j0 + c)];
    }
    float ow[16]; float obv = 0.f;
    if (layer == 3) {       // each layer-3 wave owns one output row (jw = 0..255)
#pragma unroll
        for (int k = 0; k < 16; ++k) ow[k] = outW[(size_t)jw * HDIM + lane + 64 * k];
        obv = outb[jw];
    }
    float bb[4], bfc[4];
#pragma unroll
    for (int c = 0; c < 4; ++c) {
        bb[c]  = (layer == 0) ? b0[j0 + c] : brest[(size_t)(layer - 1) * HDIM + j0 + c];
        bfc[c] = (layer == 0) ? ws[BF_FLOAT + j0 + c] : 0.f;
    }

    int minp = 0;   // cached min consumer progress (credit-based flow control)

    for (int n = 1; n <= NTOT; ++n) {
        const int par = n & 1;
        const bool xphase = (layer == 0) && (n <= SEQ);

        // backpressure (off the publish path): writing slot n kills tag n-RD;
        // downstream consumer must have captured step n-7. Own-layer skew is
        // self-limited (peers are >= step n-1 when we reach step n).
        if (minp < n - 7) {
            for (;;) {
                unsigned pv = __hip_atomic_load(&prog[cons * 32 + (lane & 31)],
                                                __ATOMIC_RELAXED, __HIP_MEMORY_SCOPE_AGENT);
                minp = wmin((int)pv);
                if (minp >= n - 7) break;
                __builtin_amdgcn_s_sleep(2);
            }
        }

        // prefetch xs row (independent of polls)
        float xv[4];
        if (xphase) {
            const float* xr = xs + (size_t)(n - 1) * IDIM;
#pragma unroll
            for (int k = 0; k < 4; ++k) xv[k] = xr[lane + 64 * k];
        }

        // parallel captures: waves 0-1 own-state halves, waves 2-3 upstream halves.
        // Each capture is gated on the producer layer's prog word (128 B polls)
        // so the heavy tagged-data polling only runs in the arrival window.
        if (wv < 2) {
            progGate(prog, layer, n - 1, lane);
            capture8(ring + ((size_t)layer * RD + ((n - 1) & (RD - 1))) * HDIM,
                     (unsigned)(n - 1), ldsOwn[par], lane, wv * 8);
        } else if (wv < 4 && !xphase) {
            const int ul = (layer == 0) ? 3 : layer - 1;
            const unsigned want = (layer == 0) ? (unsigned)(n - 1) : (unsigned)n;
            progGate(prog, ul, (int)want, lane);
            capture8(ring + ((size_t)ul * RD + (want & (RD - 1))) * HDIM,
                     want, ldsUp[par], lane, (wv - 2) * 8);
        }
        __syncthreads();
        if (threadIdx.x == 0)
            __hip_atomic_store(&prog[blockIdx.x], (unsigned)n, __ATOMIC_RELAXED, __HIP_MEMORY_SCOPE_AGENT);

        // compute this wave's 4 columns
        float a0 = 0.f, a1 = 0.f, a2 = 0.f, a3 = 0.f;
        if (xphase) {
#pragma unroll
            for (int k = 0; k < 4; ++k) {
                float x = xv[k];
                a0 += x * wx0[0][k]; a1 += x * wx0[1][k]; a2 += x * wx0[2][k]; a3 += x * wx0[3][k];
            }
        } else {
#pragma unroll
            for (int k = 0; k < 16; ++k) {
                float x = ldsUp[par][lane + 64 * k];
                a0 += x * A[0][k]; a1 += x * A[1][k]; a2 += x * A[2][k]; a3 += x * A[3][k];
            }
        }
#pragma unroll
        for (int k = 0; k < 16; ++k) {
            float y = ldsOwn[par][lane + 64 * k];
            a0 += y * B[0][k]; a1 += y * B[1][k]; a2 += y * B[2][k]; a3 += y * B[3][k];
        }
        a0 = wsum(a0); a1 = wsum(a1); a2 = wsum(a2); a3 = wsum(a3);
        const bool fph = (layer == 0) && (n > SEQ);
        float r0 = ftanh(a0 + (fph ? bfc[0] : bb[0]));
        float r1 = ftanh(a1 + (fph ? bfc[1] : bb[1]));
        float r2 = ftanh(a2 + (fph ? bfc[2] : bb[2]));
        float r3 = ftanh(a3 + (fph ? bfc[3] : bb[3]));

        // publish tagged results (lanes 0..3 store one column each)
        {
            u64* dst = ring + ((size_t)layer * RD + (n & (RD - 1))) * HDIM + j0;
            if (lane < 4) {
                float v = (lane == 0) ? r0 : (lane == 1) ? r1 : (lane == 2) ? r2 : r3;
                __hip_atomic_store(dst + lane,
                                   ((u64)(unsigned)n << 32) | (u64)__float_as_uint(v),
                                   __ATOMIC_RELAXED, __HIP_MEMORY_SCOPE_AGENT);
            }
        }

        // out row n-2 = ow . h3^{n-1}: operand already in ldsOwn — free handoff
        if (layer == 3 && n >= 2) {
            float a = 0.f;
#pragma unroll
            for (int k = 0; k < 16; ++k) a += ldsOwn[par][lane + 64 * k] * ow[k];
            a = wsum(a);
            if (lane == 0) out[(size_t)(n - 2) * IDIM + jw] = a + obv;
        }
    }

    // epilogue: final output row from h3^{NTOT}
    if (layer == 3) {
        if (wv < 2) {
            progGate(prog, 3, NTOT, lane);
            capture8(ring + ((size_t)3 * RD + (NTOT & (RD - 1))) * HDIM,
                     (unsigned)NTOT, ldsOwn[0], lane, wv * 8);
        }
        __syncthreads();
        float a = 0.f;
#pragma unroll
        for (int k = 0; k < 16; ++k) a += ldsOwn[0][lane + 64 * k] * ow[k];
        a = wsum(a);
        if (lane == 0) out[(size_t)(NTOT - 1) * IDIM + jw] = a + obv;
    }
}

// ---------------- launcher ----------------

extern "C" void kernel_launch(void* const* d_in, const int* in_sizes, int n_in,
                              void* d_out, int out_size, void* d_ws, size_t ws_size,
                              hipStream_t stream) {
    (void)in_sizes; (void)n_in; (void)out_size; (void)ws_size;
    const float* xs   = (const float*)d_in[0];
    const float* Wx0  = (const float*)d_in[1];
    const float* Wh0  = (const float*)d_in[2];
    const float* b0   = (const float*)d_in[3];
    const float* Wxr  = (const float*)d_in[4];
    const float* Whr  = (const float*)d_in[5];
    const float* brst = (const float*)d_in[6];
    const float* outW = (const float*)d_in[7];
    const float* outb = (const float*)d_in[8];
    float* ws  = (float*)d_ws;
    float* out = (float*)d_out;

    k_fuse_w<<<dim3(4, HDIM), dim3(256), 0, stream>>>(outW, Wx0, ws);
    k_fuse_b<<<dim3(4), dim3(256), 0, stream>>>(b0, outb, Wx0, ws);
    k_pack<<<dim3(32, 32, 7), dim3(32, 32), 0, stream>>>(Wh0, Wxr, Whr, ws);
    k_init<<<dim3(64), dim3(512), 0, stream>>>(ws);

    void* args[] = { (void*)&xs, (void*)&Wx0, (void*)&b0, (void*)&brst,
                     (void*)&outW, (void*)&outb, (void*)&ws, (void*)&out };
    hipError_t e = hipLaunchCooperativeKernel((void*)k_scan, dim3(NWG), dim3(TPB),
                                              args, 0, stream);
    if (e != hipSuccess) {
        // fallback: plain launch (128 WGs, <=1 per CU, trivially co-resident)
        k_scan<<<dim3(NWG), dim3(TPB), 0, stream>>>(xs, Wx0, b0, brst, outW, outb, ws, out);
    }
}